// Round 1
// baseline (1521.376 us; speedup 1.0000x reference)
//
#include <hip/hip_runtime.h>

// Problem shapes (fixed by setup_inputs, seed 0)
constexpr int B = 4, T = 4096, H = 2048, D = 256, KK = 512, N = 8192;
constexpr int WTC = 1280;  // transposed-weight cols: [0,512)=W_g1, [512,1024)=W_p1, [1024,1280)=W_obs

// ---------------------------------------------------------------------------
// Workspace layout (bytes). Total ~22.2 MiB.
constexpr size_t WS_WT    = 0;                          // float [H][1280]    10,485,760
constexpr size_t WS_BEL   = WS_WT    + (size_t)H*WTC*4; // float [N][D]        8,388,608
constexpr size_t WS_OBS   = WS_BEL   + (size_t)N*D*4;   // float [T][D]        4,194,304 (obs_mean, later obs_ang)
constexpr size_t WS_YG    = WS_OBS   + (size_t)T*D*4;   // float [B*T]            65,536
constexpr size_t WS_YP    = WS_YG    + (size_t)B*T*4;   // float [B*T]            65,536
constexpr size_t WS_OBSR  = WS_YP    + (size_t)B*T*4;   // float [T]              16,384
constexpr size_t WS_ENC   = WS_OBSR  + (size_t)T*4;     // u64   [T]              32,768
constexpr size_t WS_ACT   = WS_ENC   + (size_t)T*8;     // int   [N]              32,768
constexpr size_t WS_META  = WS_ACT   + (size_t)N*4;     // int   [64]
constexpr size_t WS_NEED  = WS_META + 256;

// ---------------------------------------------------------------------------
// Probe active_mask byte layout (jax bool could arrive as u8 / int32 / f32) and
// expand to int[N]. Values are only 0/1, so the layout is classifiable from data.
__global__ void mask_kernel(const unsigned char* raw, int* active, int* meta) {
    __shared__ int s_f32bad, s_intbad, s_nz_nonaligned;
    if (threadIdx.x == 0) { s_f32bad = 0; s_intbad = 0; s_nz_nonaligned = 0; }
    __syncthreads();
    const float* rf = (const float*)raw;
    const int*   ri = (const int*)raw;
    // Safe region in ALL layouts = first N bytes (u8 layout's full size).
    for (int i = threadIdx.x; i < N; i += blockDim.x) {
        unsigned char b = raw[i];
        if ((i & 3) && b) atomicOr(&s_nz_nonaligned, 1);
    }
    for (int e = threadIdx.x; e < N / 4; e += blockDim.x) {
        float f = rf[e]; if (!(f == 0.0f || f == 1.0f)) atomicOr(&s_f32bad, 1);
        int   v = ri[e]; if (!(v == 0 || v == 1))       atomicOr(&s_intbad, 1);
    }
    __syncthreads();
    int layout;                     // 0 = int32, 1 = u8, 2 = f32
    if (!s_f32bad)            layout = 2;  // true floats: all exactly 0.0/1.0
    else if (s_nz_nonaligned) layout = 1;  // nonzero bytes off 4B alignment => u8
    else                      layout = 0;  // 0/1 ints with clean upper bytes
    for (int n = threadIdx.x; n < N; n += blockDim.x) {
        int a;
        if (layout == 2)      a = (rf[n] != 0.0f);
        else if (layout == 1) a = (raw[n] != 0);
        else                  a = (ri[n] != 0);
        active[n] = a;
    }
    if (threadIdx.x == 0) meta[0] = layout;
}

// ---------------------------------------------------------------------------
// Transpose weights into WT[h][c] so GEMM B-tiles load fully coalesced.
__global__ void wt_kernel(const float* Wg1, const float* Wp1, const float* Wobs, float* WT) {
    __shared__ float tile[32][33];
    int hb = blockIdx.x * 32, cb = blockIdx.y * 32;
    int x = threadIdx.x & 31, y = threadIdx.x >> 5;  // 256 thr: y 0..7
    for (int i = 0; i < 32; i += 8) {
        int c = cb + y + i;
        const float* src = (c < 512) ? &Wg1[(size_t)c * H]
                         : (c < 1024) ? &Wp1[(size_t)(c - 512) * H]
                                      : &Wobs[(size_t)(c - 1024) * H];
        tile[y + i][x] = src[hb + x];
    }
    __syncthreads();
    for (int i = 0; i < 32; i += 8) {
        WT[(size_t)(hb + y + i) * WTC + cb + x] = tile[x][y + i];
    }
}

// ---------------------------------------------------------------------------
// Normalize belief rows: bel_ang[n] = beliefs[n] / max(||beliefs[n]||, 1e-8).
__global__ void belprep_kernel(const float* beliefs, float* bel_ang) {
    int wave = (blockIdx.x * blockDim.x + threadIdx.x) >> 6;
    int lane = threadIdx.x & 63;
    if (wave >= N) return;
    float4 v = ((const float4*)(beliefs + (size_t)wave * D))[lane];
    float ss = v.x * v.x + v.y * v.y + v.z * v.z + v.w * v.w;
    for (int m = 1; m < 64; m <<= 1) ss += __shfl_xor(ss, m, 64);
    float r = fmaxf(sqrtf(ss), 1e-8f);
    float inv = 1.0f / r;
    float4 o; o.x = v.x * inv; o.y = v.y * inv; o.z = v.z * inv; o.w = v.w * inv;
    ((float4*)(bel_ang + (size_t)wave * D))[lane] = o;
}

// ---------------------------------------------------------------------------
// obs_mean[T][D] = (1/B) * sum_b hidden[b] @ W_obs^T   (B-sum folded into A-tile)
// BM=32, BN=256, BK=32, 256 threads, acc 8x4 per thread.
__global__ __launch_bounds__(256) void gemm_obs_kernel(const float* hidden, const float* WT,
                                                       float* obs_mean) {
    __shared__ float As[32][33];
    __shared__ float Ws[32][260];
    int t0 = blockIdx.x * 32;
    int tx = threadIdx.x & 63, ty = threadIdx.x >> 6;  // ty 0..3
    float acc[8][4] = {};
    for (int h0 = 0; h0 < H; h0 += 32) {
        for (int q = 0; q < 4; ++q) {
            int e = threadIdx.x + q * 256;
            int r = e >> 5, kk = e & 31;
            float s = 0.0f;
            for (int b = 0; b < B; ++b)
                s += hidden[((size_t)b * T + t0 + r) * H + h0 + kk];
            As[kk][r] = s;
        }
        for (int q = 0; q < 8; ++q) {
            int e4 = threadIdx.x + q * 256;
            int kk = e4 >> 6, c4 = (e4 & 63) * 4;
            float4 w = *(const float4*)&WT[(size_t)(h0 + kk) * WTC + 1024 + c4];
            *(float4*)&Ws[kk][c4] = w;
        }
        __syncthreads();
        for (int kk = 0; kk < 32; ++kk) {
            float a[8], w[4];
            for (int i = 0; i < 8; i++) a[i] = As[kk][ty * 8 + i];
            for (int j = 0; j < 4; j++) w[j] = Ws[kk][tx + 64 * j];
            for (int i = 0; i < 8; i++)
                for (int j = 0; j < 4; j++) acc[i][j] += a[i] * w[j];
        }
        __syncthreads();
    }
    for (int i = 0; i < 8; i++)
        for (int j = 0; j < 4; j++)
            obs_mean[(size_t)(t0 + ty * 8 + i) * D + tx + 64 * j] = acc[i][j] * 0.25f;
}

// ---------------------------------------------------------------------------
// MLP GEMM with fused layer-2: per (b,t) row, y = sum_k relu(h@W1^T + b1)[k]*W2[k] + b2.
// blockIdx.y = 0 (gate path) / 1 (prec path). BM=64, BN=512, BK=16, 512 threads.
__global__ __launch_bounds__(512, 4) void gemm_mlp_kernel(
        const float* hidden, const float* WT,
        const float* b1g, const float* b1p, const float* w2g, const float* w2p,
        const float* b2g, const float* b2p, float* yg, float* yp) {
    __shared__ float As[16][65];
    __shared__ float Ws[16][516];
    int R = blockIdx.x * 64;
    int path = blockIdx.y;
    int cbase = path * 512;
    int tx = threadIdx.x & 63, ty = threadIdx.x >> 6;  // ty 0..7 (= wave id)
    float acc[8][8] = {};
    for (int h0 = 0; h0 < H; h0 += 16) {
        {   // A-tile: 64 rows x 16 k (float2 per thread)
            int r = threadIdx.x >> 3, k2 = (threadIdx.x & 7) * 2;
            float2 v = *(const float2*)&hidden[(size_t)(R + r) * H + h0 + k2];
            As[k2][r] = v.x; As[k2 + 1][r] = v.y;
        }
        for (int q = 0; q < 4; ++q) {  // W-tile: 16 x 512 (4 float4 per thread)
            int e4 = threadIdx.x + q * 512;
            int kk = e4 >> 7, c4 = (e4 & 127) * 4;
            float4 w = *(const float4*)&WT[(size_t)(h0 + kk) * WTC + cbase + c4];
            *(float4*)&Ws[kk][c4] = w;
        }
        __syncthreads();
        for (int kk = 0; kk < 16; ++kk) {
            float a[8], w[8];
            for (int i = 0; i < 8; i++) a[i] = As[kk][ty * 8 + i];   // broadcast (wave-uniform)
            for (int j = 0; j < 8; j++) w[j] = Ws[kk][tx + 64 * j];  // conflict-free
            for (int i = 0; i < 8; i++)
                for (int j = 0; j < 8; j++) acc[i][j] += a[i] * w[j];
        }
        __syncthreads();
    }
    const float* b1 = path ? b1p : b1g;
    const float* w2 = path ? w2p : w2g;
    float b2 = path ? b2p[0] : b2g[0];
    float part[8];
    for (int i = 0; i < 8; i++) {
        float s = 0.0f;
        for (int j = 0; j < 8; j++) {
            int c = tx + 64 * j;
            float z = acc[i][j] + b1[c];
            z = fmaxf(z, 0.0f);
            s += z * w2[c];
        }
        part[i] = s;
    }
    for (int m = 1; m < 64; m <<= 1)
        for (int i = 0; i < 8; i++) part[i] += __shfl_xor(part[i], m, 64);
    if (tx == 0) {
        float* dst = path ? yp : yg;
        for (int i = 0; i < 8; i++) dst[R + ty * 8 + i] = part[i] + b2;
    }
}

// ---------------------------------------------------------------------------
// Per-token: prec_mean, normalize obs_mean -> obs_beliefs (out0), obs_ang (ws,
// in-place over obs_mean), meaningful (out3), obs_r (ws), enc init.
__global__ void finalize_kernel(const float* yg, const float* yp, float* obs,
                                float* out0, float* out3, float* obs_r_ws,
                                unsigned long long* enc) {
    int t = blockIdx.x * 4 + (threadIdx.x >> 6);
    int lane = threadIdx.x & 63;
    if (t >= T) return;
    float pm = 0.0f;
    for (int b = 0; b < B; ++b) {
        float g = yg[b * T + t], p = yp[b * T + t];
        float gate = 1.0f / (1.0f + expf(-g));
        float prec = (p > 15.0f) ? p : log1pf(expf(p));
        pm += gate * prec;
    }
    pm *= (1.0f / B);
    float4 v = ((const float4*)(obs + (size_t)t * D))[lane];
    float ss = v.x * v.x + v.y * v.y + v.z * v.z + v.w * v.w;
    for (int m = 1; m < 64; m <<= 1) ss += __shfl_xor(ss, m, 64);
    float norm = sqrtf(ss);
    float na = fmaxf(norm, 1e-8f);
    float4 ob;
    ob.x = v.x / na * pm; ob.y = v.y / na * pm;
    ob.z = v.z / na * pm; ob.w = v.w / na * pm;
    float obs_r = pm * (norm / na);  // == ||obs_beliefs||
    ((float4*)(out0 + (size_t)t * D))[lane] = ob;
    float ra = fmaxf(obs_r, 1e-8f);
    float4 oa;
    oa.x = ob.x / ra; oa.y = ob.y / ra; oa.z = ob.z / ra; oa.w = ob.w / ra;
    ((float4*)(obs + (size_t)t * D))[lane] = oa;  // obs_ang for sims
    if (lane == 0) {
        out3[t] = (obs_r > 0.05f) ? 1.0f : 0.0f;
        obs_r_ws[t] = obs_r;
        enc[t] = 0ULL;
    }
}

// ---------------------------------------------------------------------------
// sims = obs_ang @ bel_ang^T with fused masked max+argmax epilogue.
// 64x64 tile, BK=64, 256 threads, 4x4 micro-tile (interleaved row/col ownership
// so LDS reads are <=2-way bank aliased = free). Combine via u64 (sim, ~idx)
// order-preserving encoding + atomicMax; ~idx => ties pick smallest idx (np.argmax).
__global__ __launch_bounds__(256) void sims_kernel(const float* obs_ang, const float* bel_ang,
                                                   const int* active, unsigned long long* enc) {
    __shared__ float Aos[64][68];
    __shared__ float Bbs[64][68];
    __shared__ unsigned long long lmax[64];
    __shared__ int act[64];
    int tb = blockIdx.x * 64, nb = blockIdx.y * 64;
    int tx = threadIdx.x & 15, ty = threadIdx.x >> 4;  // 16x16 thread grid
    if (threadIdx.x < 64) { lmax[threadIdx.x] = 0ULL; act[threadIdx.x] = active[nb + threadIdx.x]; }
    float acc[4][4] = {};
    for (int d0 = 0; d0 < D; d0 += 64) {
        for (int q = 0; q < 4; ++q) {
            int e4 = threadIdx.x + q * 256;
            int r = e4 >> 4, c4 = (e4 & 15) * 4;
            *(float4*)&Aos[r][c4] = *(const float4*)&obs_ang[(size_t)(tb + r) * D + d0 + c4];
            *(float4*)&Bbs[r][c4] = *(const float4*)&bel_ang[(size_t)(nb + r) * D + d0 + c4];
        }
        __syncthreads();
        for (int dd = 0; dd < 64; ++dd) {
            float a[4], w[4];
            for (int i = 0; i < 4; i++) a[i] = Aos[ty + 16 * i][dd];
            for (int j = 0; j < 4; j++) w[j] = Bbs[tx + 16 * j][dd];
            for (int i = 0; i < 4; i++)
                for (int j = 0; j < 4; j++) acc[i][j] += a[i] * w[j];
        }
        __syncthreads();
    }
    for (int i = 0; i < 4; i++) {
        unsigned long long best = 0ULL;
        for (int j = 0; j < 4; j++) {
            int c = tx + 16 * j;
            if (act[c]) {
                unsigned int bits = __float_as_uint(acc[i][j]);
                unsigned int e32 = (bits & 0x80000000u) ? ~bits : (bits | 0x80000000u);
                unsigned long long ev =
                    ((unsigned long long)e32 << 32) | (unsigned int)~(unsigned int)(nb + c);
                if (ev > best) best = ev;
            }
        }
        atomicMax(&lmax[ty + 16 * i], best);
    }
    __syncthreads();
    if (threadIdx.x < 64 && lmax[threadIdx.x])
        atomicMax(&enc[tb + threadIdx.x], lmax[threadIdx.x]);
}

// ---------------------------------------------------------------------------
__global__ void outw_kernel(const unsigned long long* enc, const float* obs_r_ws,
                            float* out1, float* out2) {
    int t = blockIdx.x * 256 + threadIdx.x;
    if (t >= T) return;
    unsigned long long ev = enc[t];
    float best; int idx;
    if (ev == 0ULL) { best = -3.4e38f; idx = -1; }
    else {
        unsigned int e32 = (unsigned int)(ev >> 32);
        unsigned int bits = (e32 & 0x80000000u) ? (e32 & 0x7FFFFFFFu) : ~e32;
        best = __uint_as_float(bits);
        idx = (int)~((unsigned int)(ev & 0xFFFFFFFFu));
    }
    bool meaningful = obs_r_ws[t] > 0.05f;
    bool matched = meaningful && (best > 0.5f);
    out1[t] = matched ? best : 0.0f;
    out2[t] = matched ? (float)idx : -1.0f;
}

// ---------------------------------------------------------------------------
extern "C" void kernel_launch(void* const* d_in, const int* in_sizes, int n_in,
                              void* d_out, int out_size, void* d_ws, size_t ws_size,
                              hipStream_t stream) {
    if (ws_size < WS_NEED) return;  // can't run without scratch; fail visibly

    const float* hidden  = (const float*)d_in[0];
    const float* beliefs = (const float*)d_in[1];
    const unsigned char* mask_raw = (const unsigned char*)d_in[2];
    const float* W_obs = (const float*)d_in[3];
    const float* W_g1  = (const float*)d_in[4];
    const float* b_g1  = (const float*)d_in[5];
    const float* W_g2  = (const float*)d_in[6];
    const float* b_g2  = (const float*)d_in[7];
    const float* W_p1  = (const float*)d_in[8];
    const float* b_p1  = (const float*)d_in[9];
    const float* W_p2  = (const float*)d_in[10];
    const float* b_p2  = (const float*)d_in[11];

    char* ws = (char*)d_ws;
    float* WT       = (float*)(ws + WS_WT);
    float* bel_ang  = (float*)(ws + WS_BEL);
    float* obs_buf  = (float*)(ws + WS_OBS);
    float* yg       = (float*)(ws + WS_YG);
    float* yp       = (float*)(ws + WS_YP);
    float* obs_r_ws = (float*)(ws + WS_OBSR);
    unsigned long long* enc = (unsigned long long*)(ws + WS_ENC);
    int* active     = (int*)(ws + WS_ACT);
    int* meta       = (int*)(ws + WS_META);

    float* out0 = (float*)d_out;              // obs_beliefs [T,D]
    float* out1 = out0 + (size_t)T * D;       // match_sim   [T]
    float* out2 = out1 + T;                   // matched_slot[T]
    float* out3 = out2 + T;                   // meaningful  [T]

    mask_kernel<<<1, 1024, 0, stream>>>(mask_raw, active, meta);
    wt_kernel<<<dim3(H / 32, WTC / 32), 256, 0, stream>>>(W_g1, W_p1, W_obs, WT);
    belprep_kernel<<<N / 4, 256, 0, stream>>>(beliefs, bel_ang);
    gemm_obs_kernel<<<T / 32, 256, 0, stream>>>(hidden, WT, obs_buf);
    gemm_mlp_kernel<<<dim3(B * T / 64, 2), 512, 0, stream>>>(
        hidden, WT, b_g1, b_p1, W_g2, W_p2, b_g2, b_p2, yg, yp);
    finalize_kernel<<<T / 4, 256, 0, stream>>>(yg, yp, obs_buf, out0, out3, obs_r_ws, enc);
    sims_kernel<<<dim3(T / 64, N / 64), 256, 0, stream>>>(obs_buf, bel_ang, active, enc);
    outw_kernel<<<(T + 255) / 256, 256, 0, stream>>>(enc, obs_r_ws, out1, out2);
}

// Round 2
// 778.561 us; speedup vs baseline: 1.9541x; 1.9541x over previous
//
#include <hip/hip_runtime.h>

// Shapes (fixed by setup_inputs, seed 0)
constexpr int B = 4, T = 4096, H = 2048, D = 256, KK = 512, N = 8192;
constexpr int BT = B * T;             // 16384 GEMM rows
constexpr int NML = 1024;             // MLP cols (gate 0-511 | prec 512-1023)
constexpr int NALL = 1280;            // + obs cols 1024-1279
constexpr int CAP = 1024;             // max refined tokens

typedef short bf16x8 __attribute__((ext_vector_type(8)));
typedef float f32x4  __attribute__((ext_vector_type(4)));

__device__ __forceinline__ unsigned short f2bf(float f) {
    unsigned u = __float_as_uint(f);
    return (unsigned short)((u + 0x7fffu + ((u >> 16) & 1u)) >> 16);
}
__device__ __forceinline__ void async16(const void* g, void* l) {
    __builtin_amdgcn_global_load_lds(
        (const __attribute__((address_space(1))) unsigned int*)g,
        (__attribute__((address_space(3))) unsigned int*)l, 16, 0, 0);
}
__device__ __forceinline__ unsigned long long enc_sim(float s, int idx) {
    unsigned bits = __float_as_uint(s);
    unsigned e32 = (bits & 0x80000000u) ? ~bits : (bits | 0x80000000u);
    return ((unsigned long long)e32 << 32) | (unsigned)(~(unsigned)idx);
}

// ---------------------------------------------------------------------------
// FAST-PATH workspace layout (bytes), total ~83.05 MB
constexpr size_t WS_HB   = 0;                                  // u16 [16384][2048]
constexpr size_t WS_WB   = WS_HB   + (size_t)BT * H * 2;       // u16 [1280][2048]
constexpr size_t WS_BELB = WS_WB   + (size_t)NALL * H * 2;     // u16 [8192][256]
constexpr size_t WS_OAB  = WS_BELB + (size_t)N * D * 2;        // u16 [4096][256]
constexpr size_t WS_B1C  = WS_OAB  + (size_t)T * D * 2;        // f32 [1024]
constexpr size_t WS_W2C  = WS_B1C  + 4096;                     // f32 [1024]
constexpr size_t WS_FAC  = WS_W2C  + 4096;                     // f32 [4096]
constexpr size_t WS_OBSR = WS_FAC  + 16384;                    // f32 [4096]
constexpr size_t WS_FLAG = WS_OBSR + 16384;                    // int [1024]
constexpr size_t WS_OBS  = WS_FLAG + 4096;   // ---- zeroed block starts here
constexpr size_t WS_YG   = WS_OBS  + (size_t)T * D * 4;        // f32 [16384]
constexpr size_t WS_YP   = WS_YG   + (size_t)BT * 4;           // f32 [16384]
constexpr size_t WS_ENC  = WS_YP   + (size_t)BT * 4;           // u64 [4096]
constexpr size_t WS_CNT  = WS_ENC  + (size_t)T * 8;            // int + pad
constexpr size_t WS_END  = WS_CNT  + 256;
constexpr size_t WS_ZEROSZ = WS_END - WS_OBS;

// FALLBACK (round-1 fp32) layout, total ~22.2 MB
constexpr int    WTC    = 1280;
constexpr size_t F_WT   = 0;
constexpr size_t F_BEL  = F_WT   + (size_t)H * WTC * 4;
constexpr size_t F_OBS  = F_BEL  + (size_t)N * D * 4;
constexpr size_t F_YG   = F_OBS  + (size_t)T * D * 4;
constexpr size_t F_YP   = F_YG   + (size_t)BT * 4;
constexpr size_t F_OBSR = F_YP   + (size_t)BT * 4;
constexpr size_t F_ENC  = F_OBSR + (size_t)T * 4;
constexpr size_t F_ACT  = F_ENC  + (size_t)T * 8;
constexpr size_t F_META = F_ACT  + (size_t)N * 4;
constexpr size_t F_NEED = F_META + 256;

// ---------------------------------------------------------------------------
// Shared: classify active_mask byte layout and expand to int[N].
__global__ void mask_kernel(const unsigned char* raw, int* active, int* meta) {
    __shared__ int s_f32bad, s_nz_nonaligned;
    if (threadIdx.x == 0) { s_f32bad = 0; s_nz_nonaligned = 0; }
    __syncthreads();
    const float* rf = (const float*)raw;
    const int*   ri = (const int*)raw;
    for (int i = threadIdx.x; i < N; i += blockDim.x) {
        unsigned char b = raw[i];
        if ((i & 3) && b) atomicOr(&s_nz_nonaligned, 1);
    }
    for (int e = threadIdx.x; e < N / 4; e += blockDim.x) {
        float f = rf[e]; if (!(f == 0.0f || f == 1.0f)) atomicOr(&s_f32bad, 1);
    }
    __syncthreads();
    int layout;                     // 0 = int32, 1 = u8, 2 = f32
    if (!s_f32bad)            layout = 2;
    else if (s_nz_nonaligned) layout = 1;
    else                      layout = 0;
    for (int n = threadIdx.x; n < N; n += blockDim.x) {
        int a;
        if (layout == 2)      a = (rf[n] != 0.0f);
        else if (layout == 1) a = (raw[n] != 0);
        else                  a = (ri[n] != 0);
        active[n] = a;
    }
    if (threadIdx.x == 0) meta[0] = layout;
}

// Shared: decode enc + write out1/out2.
__global__ void outw_kernel(const unsigned long long* enc, const float* obs_r_ws,
                            float* out1, float* out2) {
    int t = blockIdx.x * 256 + threadIdx.x;
    if (t >= T) return;
    unsigned long long ev = enc[t];
    float best; int idx;
    if (ev == 0ULL) { best = -3.4e38f; idx = -1; }
    else {
        unsigned int e32 = (unsigned int)(ev >> 32);
        unsigned int bits = (e32 & 0x80000000u) ? (e32 & 0x7FFFFFFFu) : ~e32;
        best = __uint_as_float(bits);
        idx = (int)~((unsigned int)(ev & 0xFFFFFFFFu));
    }
    bool meaningful = obs_r_ws[t] > 0.05f;
    bool matched = meaningful && (best > 0.5f);
    out1[t] = matched ? best : 0.0f;
    out2[t] = matched ? (float)idx : -1.0f;
}

// ===========================================================================
// FAST PATH kernels
// ===========================================================================
__global__ void conv_hidden(const float* hidden, unsigned short* hb) {
    int e = blockIdx.x * 256 + threadIdx.x;     // [0, BT*256)
    int row = e >> 8, c8 = (e & 255) * 8;
    const float* src = hidden + (size_t)row * H + c8;
    float4 v0 = *(const float4*)src;
    float4 v1 = *(const float4*)(src + 4);
    uint4 o;
    o.x = f2bf(v0.x) | ((unsigned)f2bf(v0.y) << 16);
    o.y = f2bf(v0.z) | ((unsigned)f2bf(v0.w) << 16);
    o.z = f2bf(v1.x) | ((unsigned)f2bf(v1.y) << 16);
    o.w = f2bf(v1.z) | ((unsigned)f2bf(v1.w) << 16);
    *(uint4*)(hb + (size_t)row * H + c8) = o;
}

__global__ void conv_wb(const float* Wg1, const float* Wp1, const float* Wobs,
                        unsigned short* wb) {
    int e = blockIdx.x * 256 + threadIdx.x;     // [0, NALL*256)
    int row = e >> 8, c8 = (e & 255) * 8;
    const float* src = (row < 512) ? &Wg1[(size_t)row * H]
                     : (row < 1024) ? &Wp1[(size_t)(row - 512) * H]
                                    : &Wobs[(size_t)(row - 1024) * H];
    float4 v0 = *(const float4*)(src + c8);
    float4 v1 = *(const float4*)(src + c8 + 4);
    uint4 o;
    o.x = f2bf(v0.x) | ((unsigned)f2bf(v0.y) << 16);
    o.y = f2bf(v0.z) | ((unsigned)f2bf(v0.w) << 16);
    o.z = f2bf(v1.x) | ((unsigned)f2bf(v1.y) << 16);
    o.w = f2bf(v1.z) | ((unsigned)f2bf(v1.w) << 16);
    *(uint4*)(wb + (size_t)row * H + c8) = o;
}

__global__ void conv_vec(const float* b_g1, const float* b_p1, const float* W_g2,
                         const float* W_p2, float* b1c, float* w2c) {
    int c = threadIdx.x;
    if (c < 512) { b1c[c] = b_g1[c];       w2c[c] = W_g2[c]; }
    else         { b1c[c] = b_p1[c - 512]; w2c[c] = W_p2[c - 512]; }
}

__global__ void belprep_bf(const float* beliefs, unsigned short* belb) {
    int wave = (blockIdx.x * blockDim.x + threadIdx.x) >> 6;
    int lane = threadIdx.x & 63;
    if (wave >= N) return;
    float4 v = ((const float4*)(beliefs + (size_t)wave * D))[lane];
    float ss = v.x * v.x + v.y * v.y + v.z * v.z + v.w * v.w;
    for (int m = 1; m < 64; m <<= 1) ss += __shfl_xor(ss, m, 64);
    float inv = 1.0f / fmaxf(sqrtf(ss), 1e-8f);
    uint2 o;
    o.x = f2bf(v.x * inv) | ((unsigned)f2bf(v.y * inv) << 16);
    o.y = f2bf(v.z * inv) | ((unsigned)f2bf(v.w * inv) << 16);
    *(uint2*)(belb + (size_t)wave * D + lane * 4) = o;
}

// One MFMA GEMM for all projections: A = h_bf16 [16384][2048], B = wb [1280][2048]
// (row n = output col, bf16, [n][k] layout). 128x128 tiles, BK=32, m97-style
// global_load_lds staging. Epilogue per col-block: MLP (relu+w2 dot -> atomicAdd y)
// or obs (atomicAdd obs_buf with B-mean fold).
__global__ __launch_bounds__(256) void big_gemm(const unsigned short* Ab, const unsigned short* Bb,
                                                const float* b1c, const float* w2c,
                                                float* yg, float* yp, float* obs_buf) {
    __shared__ unsigned short As[128 * 32];
    __shared__ unsigned short Bs[128 * 32];
    __shared__ float b1s[128], w2s[128];
    int tid = threadIdx.x;
    int mb = blockIdx.x, nb = blockIdx.y;
    int m0 = mb * 128, n0 = nb * 128;
    bool is_mlp = (nb < 8);
    if (is_mlp && tid < 128) { b1s[tid] = b1c[n0 + tid]; w2s[tid] = w2c[n0 + tid]; }
    int wave = tid >> 6, lane = tid & 63;
    int wr = wave >> 1, wc = wave & 1;
    int quad = lane >> 4, mrow = lane & 15;
    f32x4 acc[4][4] = {};
    const unsigned short* gA = Ab + (size_t)(m0 + (tid >> 2)) * H + (tid & 3) * 8;
    const unsigned short* gB = Bb + (size_t)(n0 + (tid >> 2)) * H + (tid & 3) * 8;
    char* lA = (char*)As + wave * 1024;
    char* lB = (char*)Bs + wave * 1024;
    for (int k0 = 0; k0 < H; k0 += 32) {
        async16(gA + k0, lA);
        async16(gA + (size_t)64 * H + k0, lA + 4096);
        async16(gB + k0, lB);
        async16(gB + (size_t)64 * H + k0, lB + 4096);
        __syncthreads();
        bf16x8 a[4], b[4];
        for (int i = 0; i < 4; i++) a[i] = *(const bf16x8*)&As[(wr * 64 + i * 16 + mrow) * 32 + quad * 8];
        for (int j = 0; j < 4; j++) b[j] = *(const bf16x8*)&Bs[(wc * 64 + j * 16 + mrow) * 32 + quad * 8];
        for (int i = 0; i < 4; i++)
            for (int j = 0; j < 4; j++)
                acc[i][j] = __builtin_amdgcn_mfma_f32_16x16x32_bf16(a[i], b[j], acc[i][j], 0, 0, 0);
        __syncthreads();
    }
    if (is_mlp) {
        float* y = (nb < 4) ? yg : yp;
        for (int i = 0; i < 4; i++) {
            int row_g = m0 + wr * 64 + i * 16 + quad * 4;
            for (int r = 0; r < 4; r++) {
                float s = 0.0f;
                for (int j = 0; j < 4; j++) {
                    int cl = wc * 64 + j * 16 + mrow;
                    float z = acc[i][j][r] + b1s[cl];
                    z = fmaxf(z, 0.0f);
                    s += z * w2s[cl];
                }
                s += __shfl_xor(s, 1); s += __shfl_xor(s, 2);
                s += __shfl_xor(s, 4); s += __shfl_xor(s, 8);
                if (mrow == 0) atomicAdd(&y[row_g + r], s);
            }
        }
    } else {
        for (int i = 0; i < 4; i++)
            for (int r = 0; r < 4; r++) {
                int row_g = m0 + wr * 64 + i * 16 + quad * 4 + r;
                int t = row_g & (T - 1);
                for (int j = 0; j < 4; j++) {
                    int d = n0 - 1024 + wc * 64 + j * 16 + mrow;
                    atomicAdd(&obs_buf[(size_t)t * D + d], acc[i][j][r] * 0.25f);
                }
            }
    }
}

// Per-token epilogue: pm (approx), norms, out0, obs_ang bf16, flags + y-row zeroing.
__global__ void finalize_fast(const float* yg, const float* yp, const float* obs_buf,
                              const float* b_g2, const float* b_p2,
                              float* out0, float* out3, float* obs_r_ws, float* fac,
                              unsigned short* oab, int* flaglist, int* flagcnt,
                              float* yg_mut, float* yp_mut) {
    int t = blockIdx.x * 4 + (threadIdx.x >> 6);
    int lane = threadIdx.x & 63;
    if (t >= T) return;
    float bg2 = b_g2[0], bp2 = b_p2[0];
    float pm = 0.0f;
    for (int b = 0; b < B; ++b) {
        float g = yg[b * T + t] + bg2;
        float p = yp[b * T + t] + bp2;
        float gate = 1.0f / (1.0f + expf(-g));
        float prec = (p > 20.0f) ? p : log1pf(expf(p));
        pm += gate * prec;
    }
    pm *= 0.25f;
    float4 v = ((const float4*)(obs_buf + (size_t)t * D))[lane];
    float ss = v.x * v.x + v.y * v.y + v.z * v.z + v.w * v.w;
    for (int m = 1; m < 64; m <<= 1) ss += __shfl_xor(ss, m, 64);
    float norm = sqrtf(ss);
    float na = fmaxf(norm, 1e-8f);
    float f = norm / na;
    float inv = 1.0f / na;
    float ax = v.x * inv, ay = v.y * inv, az = v.z * inv, aw = v.w * inv;
    float4 ob; ob.x = ax * pm; ob.y = ay * pm; ob.z = az * pm; ob.w = aw * pm;
    ((float4*)(out0 + (size_t)t * D))[lane] = ob;
    uint2 oa;
    oa.x = f2bf(ax) | ((unsigned)f2bf(ay) << 16);
    oa.y = f2bf(az) | ((unsigned)f2bf(aw) << 16);
    *(uint2*)(oab + (size_t)t * D + lane * 4) = oa;
    if (lane == 0) {
        float obs_r = pm * f;
        obs_r_ws[t] = obs_r;
        fac[t] = f;
        out3[t] = (obs_r > 0.05f) ? 1.0f : 0.0f;
        if (fabsf(obs_r - 0.05f) < 2.5e-3f) {
            int idx = atomicAdd(flagcnt, 1);
            if (idx < CAP) {
                flaglist[idx] = t;
                for (int b = 0; b < B; ++b) { yg_mut[b * T + t] = 0.0f; yp_mut[b * T + t] = 0.0f; }
            }
        }
    }
}

// Exact fp32 MLP recompute for flagged rows (gathered GEMM, BM=16, BN=128, BK=32).
__global__ __launch_bounds__(256) void refine_mlp(const float* hidden,
        const float* Wg1, const float* Wp1, const float* b1c, const float* w2c,
        const int* flaglist, const int* flagcnt, float* yg, float* yp) {
    int nflag = min(*flagcnt, CAP);
    int nrows = nflag * 4;
    int rt = blockIdx.x;
    if (rt * 16 >= nrows) return;
    int ct = blockIdx.y;
    int cbase = ct * 128;                       // [0,1024)
    const float* W1 = (cbase < 512) ? Wg1 : Wp1;
    int wrow0 = cbase & 511;
    __shared__ float As2[16][33];
    __shared__ float Ws2[128][33];
    __shared__ float red[16][129];
    __shared__ int rowg_s[16];
    int tid = threadIdx.x;
    if (tid < 16) {
        int fr = rt * 16 + tid;
        int rg = -1;
        if (fr < nrows) { int tok = flaglist[fr >> 2]; int b = fr & 3; rg = b * T + tok; }
        rowg_s[tid] = rg;
    }
    __syncthreads();
    float acc[8] = {};
    int c = tid & 127, half = tid >> 7;
    for (int k0 = 0; k0 < H; k0 += 32) {
        { int r = tid >> 4, hc = (tid & 15) * 2;
          int rg = rowg_s[r];
          float x0 = 0.0f, x1 = 0.0f;
          if (rg >= 0) { float2 v = *(const float2*)&hidden[(size_t)rg * H + k0 + hc]; x0 = v.x; x1 = v.y; }
          As2[r][hc] = x0; As2[r][hc + 1] = x1; }
        for (int q = 0; q < 4; ++q) {
            int e = tid + q * 256;
            int col = e >> 3, hc = (e & 7) * 4;
            float4 w = *(const float4*)&W1[(size_t)(wrow0 + col) * H + k0 + hc];
            Ws2[col][hc] = w.x; Ws2[col][hc + 1] = w.y; Ws2[col][hc + 2] = w.z; Ws2[col][hc + 3] = w.w;
        }
        __syncthreads();
        for (int kk = 0; kk < 32; ++kk) {
            float w = Ws2[c][kk];
            for (int i = 0; i < 8; i++) acc[i] += As2[half * 8 + i][kk] * w;
        }
        __syncthreads();
    }
    int cg = cbase + c;
    float b1v = b1c[cg], w2v = w2c[cg];
    for (int i = 0; i < 8; i++) {
        float z = fmaxf(acc[i] + b1v, 0.0f);
        red[half * 8 + i][c] = z * w2v;
    }
    __syncthreads();
    int row = tid >> 4, seg = tid & 15;
    float s = 0.0f;
    for (int q = 0; q < 8; q++) s += red[row][seg * 8 + q];
    s += __shfl_xor(s, 1); s += __shfl_xor(s, 2); s += __shfl_xor(s, 4); s += __shfl_xor(s, 8);
    if (seg == 0) {
        int rg = rowg_s[row];
        if (rg >= 0) {
            float* y = (cbase < 512) ? yg : yp;
            atomicAdd(&y[rg], s);
        }
    }
}

__global__ void refine_pm(const float* yg, const float* yp, const float* b_g2, const float* b_p2,
                          const int* flagcnt, const int* flaglist, const float* fac,
                          float* obs_r_ws, float* out3) {
    int nflag = min(*flagcnt, CAP);
    int idx = blockIdx.x * 64 + threadIdx.x;
    if (idx >= nflag) return;
    int t = flaglist[idx];
    float bg2 = b_g2[0], bp2 = b_p2[0];
    float pm = 0.0f;
    for (int b = 0; b < B; ++b) {
        float g = yg[b * T + t] + bg2;
        float p = yp[b * T + t] + bp2;
        float gate = 1.0f / (1.0f + expf(-g));
        float prec = (p > 20.0f) ? p : log1pf(expf(p));
        pm += gate * prec;
    }
    pm *= 0.25f;
    float obs_r = pm * fac[t];
    obs_r_ws[t] = obs_r;
    out3[t] = (obs_r > 0.05f) ? 1.0f : 0.0f;
}

// sims = obs_ang @ bel_ang^T (bf16 MFMA) with fused masked max/argmax epilogue.
__global__ __launch_bounds__(256) void sims_mfma(const unsigned short* oab, const unsigned short* belb,
                                                 const int* active, unsigned long long* enc) {
    __shared__ unsigned short As[128 * 32];
    __shared__ unsigned short Bs[128 * 32];
    __shared__ int acts[128];
    int tid = threadIdx.x;
    int mb = blockIdx.x, nb = blockIdx.y;
    int m0 = mb * 128, n0 = nb * 128;
    if (tid < 128) acts[tid] = active[n0 + tid];
    int wave = tid >> 6, lane = tid & 63;
    int wr = wave >> 1, wc = wave & 1;
    int quad = lane >> 4, mrow = lane & 15;
    f32x4 acc[4][4] = {};
    const unsigned short* gA = oab + (size_t)(m0 + (tid >> 2)) * D + (tid & 3) * 8;
    const unsigned short* gB = belb + (size_t)(n0 + (tid >> 2)) * D + (tid & 3) * 8;
    char* lA = (char*)As + wave * 1024;
    char* lB = (char*)Bs + wave * 1024;
    for (int k0 = 0; k0 < D; k0 += 32) {
        async16(gA + k0, lA);
        async16(gA + (size_t)64 * D + k0, lA + 4096);
        async16(gB + k0, lB);
        async16(gB + (size_t)64 * D + k0, lB + 4096);
        __syncthreads();
        bf16x8 a[4], b[4];
        for (int i = 0; i < 4; i++) a[i] = *(const bf16x8*)&As[(wr * 64 + i * 16 + mrow) * 32 + quad * 8];
        for (int j = 0; j < 4; j++) b[j] = *(const bf16x8*)&Bs[(wc * 64 + j * 16 + mrow) * 32 + quad * 8];
        for (int i = 0; i < 4; i++)
            for (int j = 0; j < 4; j++)
                acc[i][j] = __builtin_amdgcn_mfma_f32_16x16x32_bf16(a[i], b[j], acc[i][j], 0, 0, 0);
        __syncthreads();
    }
    for (int i = 0; i < 4; i++)
        for (int r = 0; r < 4; r++) {
            int row_g = m0 + wr * 64 + i * 16 + quad * 4 + r;
            unsigned long long best = 0ULL;
            for (int j = 0; j < 4; j++) {
                int cl = wc * 64 + j * 16 + mrow;
                if (acts[cl]) {
                    unsigned long long ev = enc_sim(acc[i][j][r], n0 + cl);
                    if (ev > best) best = ev;
                }
            }
            best = max(best, __shfl_xor(best, 1));
            best = max(best, __shfl_xor(best, 2));
            best = max(best, __shfl_xor(best, 4));
            best = max(best, __shfl_xor(best, 8));
            if (mrow == 0 && best) atomicMax(&enc[row_g], best);
        }
}

// ===========================================================================
// FALLBACK (round-1 fp32 pipeline, proven correct)
// ===========================================================================
__global__ void wt_kernel(const float* Wg1, const float* Wp1, const float* Wobs, float* WT) {
    __shared__ float tile[32][33];
    int hb = blockIdx.x * 32, cb = blockIdx.y * 32;
    int x = threadIdx.x & 31, y = threadIdx.x >> 5;
    for (int i = 0; i < 32; i += 8) {
        int c = cb + y + i;
        const float* src = (c < 512) ? &Wg1[(size_t)c * H]
                         : (c < 1024) ? &Wp1[(size_t)(c - 512) * H]
                                      : &Wobs[(size_t)(c - 1024) * H];
        tile[y + i][x] = src[hb + x];
    }
    __syncthreads();
    for (int i = 0; i < 32; i += 8)
        WT[(size_t)(hb + y + i) * WTC + cb + x] = tile[x][y + i];
}

__global__ void belprep_kernel(const float* beliefs, float* bel_ang) {
    int wave = (blockIdx.x * blockDim.x + threadIdx.x) >> 6;
    int lane = threadIdx.x & 63;
    if (wave >= N) return;
    float4 v = ((const float4*)(beliefs + (size_t)wave * D))[lane];
    float ss = v.x * v.x + v.y * v.y + v.z * v.z + v.w * v.w;
    for (int m = 1; m < 64; m <<= 1) ss += __shfl_xor(ss, m, 64);
    float inv = 1.0f / fmaxf(sqrtf(ss), 1e-8f);
    float4 o; o.x = v.x * inv; o.y = v.y * inv; o.z = v.z * inv; o.w = v.w * inv;
    ((float4*)(bel_ang + (size_t)wave * D))[lane] = o;
}

__global__ __launch_bounds__(256) void gemm_obs_kernel(const float* hidden, const float* WT,
                                                       float* obs_mean) {
    __shared__ float As[32][33];
    __shared__ float Ws[32][260];
    int t0 = blockIdx.x * 32;
    int tx = threadIdx.x & 63, ty = threadIdx.x >> 6;
    float acc[8][4] = {};
    for (int h0 = 0; h0 < H; h0 += 32) {
        for (int q = 0; q < 4; ++q) {
            int e = threadIdx.x + q * 256;
            int r = e >> 5, kk = e & 31;
            float s = 0.0f;
            for (int b = 0; b < B; ++b) s += hidden[((size_t)b * T + t0 + r) * H + h0 + kk];
            As[kk][r] = s;
        }
        for (int q = 0; q < 8; ++q) {
            int e4 = threadIdx.x + q * 256;
            int kk = e4 >> 6, c4 = (e4 & 63) * 4;
            *(float4*)&Ws[kk][c4] = *(const float4*)&WT[(size_t)(h0 + kk) * WTC + 1024 + c4];
        }
        __syncthreads();
        for (int kk = 0; kk < 32; ++kk) {
            float a[8], w[4];
            for (int i = 0; i < 8; i++) a[i] = As[kk][ty * 8 + i];
            for (int j = 0; j < 4; j++) w[j] = Ws[kk][tx + 64 * j];
            for (int i = 0; i < 8; i++)
                for (int j = 0; j < 4; j++) acc[i][j] += a[i] * w[j];
        }
        __syncthreads();
    }
    for (int i = 0; i < 8; i++)
        for (int j = 0; j < 4; j++)
            obs_mean[(size_t)(t0 + ty * 8 + i) * D + tx + 64 * j] = acc[i][j] * 0.25f;
}

__global__ __launch_bounds__(512, 4) void gemm_mlp_kernel(
        const float* hidden, const float* WT,
        const float* b1g, const float* b1p, const float* w2g, const float* w2p,
        const float* b2g, const float* b2p, float* yg, float* yp) {
    __shared__ float As[16][65];
    __shared__ float Ws[16][516];
    int R = blockIdx.x * 64;
    int path = blockIdx.y;
    int cbase = path * 512;
    int tx = threadIdx.x & 63, ty = threadIdx.x >> 6;
    float acc[8][8] = {};
    for (int h0 = 0; h0 < H; h0 += 16) {
        {   int r = threadIdx.x >> 3, k2 = (threadIdx.x & 7) * 2;
            float2 v = *(const float2*)&hidden[(size_t)(R + r) * H + h0 + k2];
            As[k2][r] = v.x; As[k2 + 1][r] = v.y; }
        for (int q = 0; q < 4; ++q) {
            int e4 = threadIdx.x + q * 512;
            int kk = e4 >> 7, c4 = (e4 & 127) * 4;
            *(float4*)&Ws[kk][c4] = *(const float4*)&WT[(size_t)(h0 + kk) * WTC + cbase + c4];
        }
        __syncthreads();
        for (int kk = 0; kk < 16; ++kk) {
            float a[8], w[8];
            for (int i = 0; i < 8; i++) a[i] = As[kk][ty * 8 + i];
            for (int j = 0; j < 8; j++) w[j] = Ws[kk][tx + 64 * j];
            for (int i = 0; i < 8; i++)
                for (int j = 0; j < 8; j++) acc[i][j] += a[i] * w[j];
        }
        __syncthreads();
    }
    const float* b1 = path ? b1p : b1g;
    const float* w2 = path ? w2p : w2g;
    float b2 = path ? b2p[0] : b2g[0];
    float part[8];
    for (int i = 0; i < 8; i++) {
        float s = 0.0f;
        for (int j = 0; j < 8; j++) {
            int c = tx + 64 * j;
            float z = fmaxf(acc[i][j] + b1[c], 0.0f);
            s += z * w2[c];
        }
        part[i] = s;
    }
    for (int m = 1; m < 64; m <<= 1)
        for (int i = 0; i < 8; i++) part[i] += __shfl_xor(part[i], m, 64);
    if (tx == 0) {
        float* dst = path ? yp : yg;
        for (int i = 0; i < 8; i++) dst[R + ty * 8 + i] = part[i] + b2;
    }
}

__global__ void finalize_kernel(const float* yg, const float* yp, float* obs,
                                float* out0, float* out3, float* obs_r_ws,
                                unsigned long long* enc) {
    int t = blockIdx.x * 4 + (threadIdx.x >> 6);
    int lane = threadIdx.x & 63;
    if (t >= T) return;
    float pm = 0.0f;
    for (int b = 0; b < B; ++b) {
        float g = yg[b * T + t], p = yp[b * T + t];
        float gate = 1.0f / (1.0f + expf(-g));
        float prec = (p > 15.0f) ? p : log1pf(expf(p));
        pm += gate * prec;
    }
    pm *= (1.0f / B);
    float4 v = ((const float4*)(obs + (size_t)t * D))[lane];
    float ss = v.x * v.x + v.y * v.y + v.z * v.z + v.w * v.w;
    for (int m = 1; m < 64; m <<= 1) ss += __shfl_xor(ss, m, 64);
    float norm = sqrtf(ss);
    float na = fmaxf(norm, 1e-8f);
    float4 ob;
    ob.x = v.x / na * pm; ob.y = v.y / na * pm;
    ob.z = v.z / na * pm; ob.w = v.w / na * pm;
    float obs_r = pm * (norm / na);
    ((float4*)(out0 + (size_t)t * D))[lane] = ob;
    float ra = fmaxf(obs_r, 1e-8f);
    float4 oa;
    oa.x = ob.x / ra; oa.y = ob.y / ra; oa.z = ob.z / ra; oa.w = ob.w / ra;
    ((float4*)(obs + (size_t)t * D))[lane] = oa;
    if (lane == 0) {
        out3[t] = (obs_r > 0.05f) ? 1.0f : 0.0f;
        obs_r_ws[t] = obs_r;
        enc[t] = 0ULL;
    }
}

__global__ __launch_bounds__(256) void sims_kernel(const float* obs_ang, const float* bel_ang,
                                                   const int* active, unsigned long long* enc) {
    __shared__ float Aos[64][68];
    __shared__ float Bbs[64][68];
    __shared__ unsigned long long lmax[64];
    __shared__ int act[64];
    int tb = blockIdx.x * 64, nb = blockIdx.y * 64;
    int tx = threadIdx.x & 15, ty = threadIdx.x >> 4;
    if (threadIdx.x < 64) { lmax[threadIdx.x] = 0ULL; act[threadIdx.x] = active[nb + threadIdx.x]; }
    float acc[4][4] = {};
    for (int d0 = 0; d0 < D; d0 += 64) {
        for (int q = 0; q < 4; ++q) {
            int e4 = threadIdx.x + q * 256;
            int r = e4 >> 4, c4 = (e4 & 15) * 4;
            *(float4*)&Aos[r][c4] = *(const float4*)&obs_ang[(size_t)(tb + r) * D + d0 + c4];
            *(float4*)&Bbs[r][c4] = *(const float4*)&bel_ang[(size_t)(nb + r) * D + d0 + c4];
        }
        __syncthreads();
        for (int dd = 0; dd < 64; ++dd) {
            float a[4], w[4];
            for (int i = 0; i < 4; i++) a[i] = Aos[ty + 16 * i][dd];
            for (int j = 0; j < 4; j++) w[j] = Bbs[tx + 16 * j][dd];
            for (int i = 0; i < 4; i++)
                for (int j = 0; j < 4; j++) acc[i][j] += a[i] * w[j];
        }
        __syncthreads();
    }
    for (int i = 0; i < 4; i++) {
        unsigned long long best = 0ULL;
        for (int j = 0; j < 4; j++) {
            int c = tx + 16 * j;
            if (act[c]) {
                unsigned long long ev = enc_sim(acc[i][j], nb + c);
                if (ev > best) best = ev;
            }
        }
        atomicMax(&lmax[ty + 16 * i], best);
    }
    __syncthreads();
    if (threadIdx.x < 64 && lmax[threadIdx.x])
        atomicMax(&enc[tb + threadIdx.x], lmax[threadIdx.x]);
}

// ===========================================================================
extern "C" void kernel_launch(void* const* d_in, const int* in_sizes, int n_in,
                              void* d_out, int out_size, void* d_ws, size_t ws_size,
                              hipStream_t stream) {
    const float* hidden  = (const float*)d_in[0];
    const float* beliefs = (const float*)d_in[1];
    const unsigned char* mask_raw = (const unsigned char*)d_in[2];
    const float* W_obs = (const float*)d_in[3];
    const float* W_g1  = (const float*)d_in[4];
    const float* b_g1  = (const float*)d_in[5];
    const float* W_g2  = (const float*)d_in[6];
    const float* b_g2  = (const float*)d_in[7];
    const float* W_p1  = (const float*)d_in[8];
    const float* b_p1  = (const float*)d_in[9];
    const float* W_p2  = (const float*)d_in[10];
    const float* b_p2  = (const float*)d_in[11];

    float* out0 = (float*)d_out;
    float* out1 = out0 + (size_t)T * D;
    float* out2 = out1 + T;
    float* out3 = out2 + T;
    char* ws = (char*)d_ws;

    if (ws_size >= WS_END) {
        // ---------------- fast path (bf16 MFMA) ----------------
        unsigned short* hb   = (unsigned short*)(ws + WS_HB);
        unsigned short* wb   = (unsigned short*)(ws + WS_WB);
        unsigned short* belb = (unsigned short*)(ws + WS_BELB);
        unsigned short* oab  = (unsigned short*)(ws + WS_OAB);
        float* b1c     = (float*)(ws + WS_B1C);
        float* w2c     = (float*)(ws + WS_W2C);
        float* fac     = (float*)(ws + WS_FAC);
        float* obs_r   = (float*)(ws + WS_OBSR);
        int*   flaglist= (int*)(ws + WS_FLAG);
        float* obs_buf = (float*)(ws + WS_OBS);
        float* yg      = (float*)(ws + WS_YG);
        float* yp      = (float*)(ws + WS_YP);
        unsigned long long* enc = (unsigned long long*)(ws + WS_ENC);
        int*   flagcnt = (int*)(ws + WS_CNT);
        int*   active  = (int*)(ws + WS_FLAG);  // reuse? NO — need both. Use meta area:
        // active needs N ints = 32KB; carve from hb tail is unsafe. Place after WS_END? No.
        // Use a dedicated region: overlay on wb tail is unsafe too. Simplest: put active
        // in the last 32KB of bel_ang bf16 region? Also unsafe. -> use stack region below.
        (void)active;
        // dedicated active buffer: carved from unused upper part of flag page is too small,
        // so append: we ensured ws_size >= WS_END; check for extra 64KB:
        int* active2 = (int*)(ws + WS_END);
        bool have_active = (ws_size >= WS_END + (size_t)N * 4 + 256);
        if (!have_active) {
            // extremely unlikely; fall back to fp32 path requirements below if possible
        } else {
            hipMemsetAsync(ws + WS_OBS, 0, WS_ZEROSZ, stream);
            mask_kernel<<<1, 1024, 0, stream>>>(mask_raw, active2, (int*)(ws + WS_CNT + 128));
            conv_vec<<<1, 1024, 0, stream>>>(b_g1, b_p1, W_g2, W_p2, b1c, w2c);
            conv_wb<<<NALL, 256, 0, stream>>>(W_g1, W_p1, W_obs, wb);
            conv_hidden<<<BT, 256, 0, stream>>>(hidden, hb);
            belprep_bf<<<N / 4, 256, 0, stream>>>(beliefs, belb);
            big_gemm<<<dim3(BT / 128, NALL / 128), 256, 0, stream>>>(hb, wb, b1c, w2c, yg, yp, obs_buf);
            finalize_fast<<<T / 4, 256, 0, stream>>>(yg, yp, obs_buf, b_g2, b_p2,
                                                     out0, out3, obs_r, fac, oab,
                                                     flaglist, flagcnt, yg, yp);
            refine_mlp<<<dim3(CAP * 4 / 16, 8), 256, 0, stream>>>(hidden, W_g1, W_p1, b1c, w2c,
                                                                  flaglist, flagcnt, yg, yp);
            refine_pm<<<CAP / 64, 64, 0, stream>>>(yg, yp, b_g2, b_p2, flagcnt, flaglist,
                                                   fac, obs_r, out3);
            sims_mfma<<<dim3(T / 128, N / 128), 256, 0, stream>>>(oab, belb, active2, enc);
            outw_kernel<<<(T + 255) / 256, 256, 0, stream>>>(enc, obs_r, out1, out2);
            return;
        }
    }

    if (ws_size < F_NEED) return;
    // ---------------- fallback (round-1 fp32, proven) ----------------
    float* WT       = (float*)(ws + F_WT);
    float* bel_ang  = (float*)(ws + F_BEL);
    float* obs_buf  = (float*)(ws + F_OBS);
    float* yg       = (float*)(ws + F_YG);
    float* yp       = (float*)(ws + F_YP);
    float* obs_r_ws = (float*)(ws + F_OBSR);
    unsigned long long* enc = (unsigned long long*)(ws + F_ENC);
    int* active     = (int*)(ws + F_ACT);
    int* meta       = (int*)(ws + F_META);

    mask_kernel<<<1, 1024, 0, stream>>>(mask_raw, active, meta);
    wt_kernel<<<dim3(H / 32, WTC / 32), 256, 0, stream>>>(W_g1, W_p1, W_obs, WT);
    belprep_kernel<<<N / 4, 256, 0, stream>>>(beliefs, bel_ang);
    gemm_obs_kernel<<<T / 32, 256, 0, stream>>>(hidden, WT, obs_buf);
    gemm_mlp_kernel<<<dim3(BT / 64, 2), 512, 0, stream>>>(
        hidden, WT, b_g1, b_p1, W_g2, W_p2, b_g2, b_p2, yg, yp);
    finalize_kernel<<<T / 4, 256, 0, stream>>>(yg, yp, obs_buf, out0, out3, obs_r_ws, enc);
    sims_kernel<<<dim3(T / 64, N / 64), 256, 0, stream>>>(obs_buf, bel_ang, active, enc);
    outw_kernel<<<(T + 255) / 256, 256, 0, stream>>>(enc, obs_r_ws, out1, out2);
}

// Round 3
// 491.908 us; speedup vs baseline: 3.0928x; 1.5827x over previous
//
#include <hip/hip_runtime.h>

// Shapes (fixed by setup_inputs, seed 0)
constexpr int B = 4, T = 4096, H = 2048, D = 256, KK = 512, N = 8192;
constexpr int BT = B * T;             // 16384 GEMM rows
constexpr int NALL = 1280;            // GEMM cols: gate 0-511 | prec 512-1023 | obs 1024-1279
constexpr int CAP = 1536;             // max refined tokens (band expected ~400-900)

typedef short bf16x8 __attribute__((ext_vector_type(8)));
typedef float f32x4  __attribute__((ext_vector_type(4)));

__device__ __forceinline__ unsigned short f2bf(float f) {
    unsigned u = __float_as_uint(f);
    return (unsigned short)((u + 0x7fffu + ((u >> 16) & 1u)) >> 16);
}
__device__ __forceinline__ float bf2f(unsigned short h) {
    return __uint_as_float((unsigned)h << 16);
}
__device__ __forceinline__ void async16(const void* g, void* l) {
    __builtin_amdgcn_global_load_lds(
        (const __attribute__((address_space(1))) unsigned int*)g,
        (__attribute__((address_space(3))) unsigned int*)l, 16, 0, 0);
}
__device__ __forceinline__ unsigned long long enc_sim(float s, int idx) {
    unsigned bits = __float_as_uint(s);
    unsigned e32 = (bits & 0x80000000u) ? ~bits : (bits | 0x80000000u);
    return ((unsigned long long)e32 << 32) | (unsigned)(~(unsigned)idx);
}

// ---------------------------------------------------------------------------
// FAST-PATH workspace layout (bytes), total ~83.1 MB
constexpr size_t WS_HB   = 0;                                  // u16 [16384][2048]
constexpr size_t WS_WB   = WS_HB   + (size_t)BT * H * 2;       // u16 [1280][2048]
constexpr size_t WS_BELB = WS_WB   + (size_t)NALL * H * 2;     // u16 [8192][256]
constexpr size_t WS_OAB  = WS_BELB + (size_t)N * D * 2;        // u16 [4096][256]
constexpr size_t WS_B1C  = WS_OAB  + (size_t)T * D * 2;        // f32 [1024]
constexpr size_t WS_W2C  = WS_B1C  + 4096;                     // f32 [1024]
constexpr size_t WS_FAC  = WS_W2C  + 4096;                     // f32 [4096]
constexpr size_t WS_OBSR = WS_FAC  + 16384;                    // f32 [4096]
constexpr size_t WS_FLAG = WS_OBSR + 16384;                    // int [CAP]
constexpr size_t WS_OBS  = WS_FLAG + (size_t)CAP * 4;  // ---- zeroed block ----
constexpr size_t WS_YG   = WS_OBS  + (size_t)T * D * 4;        // f32 [16384]
constexpr size_t WS_YP   = WS_YG   + (size_t)BT * 4;           // f32 [16384]
constexpr size_t WS_ENC  = WS_YP   + (size_t)BT * 4;           // u64 [4096]
constexpr size_t WS_CNT  = WS_ENC  + (size_t)T * 8;            // int + pad
constexpr size_t WS_ACTV = WS_CNT  + 256;            // ---- end zeroed block ----
constexpr size_t WS_META = WS_ACTV + (size_t)N * 4;            // int [64]
constexpr size_t WS_NEEDF = WS_META + 256;
constexpr size_t WS_ZEROSZ = WS_ACTV - WS_OBS;

// FALLBACK (round-1 fp32) layout, total ~22.2 MB
constexpr int    WTC    = 1280;
constexpr size_t F_WT   = 0;
constexpr size_t F_BEL  = F_WT   + (size_t)H * WTC * 4;
constexpr size_t F_OBS  = F_BEL  + (size_t)N * D * 4;
constexpr size_t F_YG   = F_OBS  + (size_t)T * D * 4;
constexpr size_t F_YP   = F_YG   + (size_t)BT * 4;
constexpr size_t F_OBSR = F_YP   + (size_t)BT * 4;
constexpr size_t F_ENC  = F_OBSR + (size_t)T * 4;
constexpr size_t F_ACT  = F_ENC  + (size_t)T * 8;
constexpr size_t F_META = F_ACT  + (size_t)N * 4;
constexpr size_t F_NEED = F_META + 256;

// ---------------------------------------------------------------------------
// Classify active_mask byte layout (u8 / int32 / f32) and expand to int[N].
__global__ void mask_kernel(const unsigned char* raw, int* active, int* meta) {
    __shared__ int s_f32bad, s_nz_nonaligned;
    if (threadIdx.x == 0) { s_f32bad = 0; s_nz_nonaligned = 0; }
    __syncthreads();
    const float* rf = (const float*)raw;
    const int*   ri = (const int*)raw;
    for (int i = threadIdx.x; i < N; i += blockDim.x) {
        unsigned char b = raw[i];
        if ((i & 3) && b) atomicOr(&s_nz_nonaligned, 1);
    }
    for (int e = threadIdx.x; e < N / 4; e += blockDim.x) {
        float f = rf[e]; if (!(f == 0.0f || f == 1.0f)) atomicOr(&s_f32bad, 1);
    }
    __syncthreads();
    int layout;                     // 0 = int32, 1 = u8, 2 = f32
    if (!s_f32bad)            layout = 2;
    else if (s_nz_nonaligned) layout = 1;
    else                      layout = 0;
    for (int n = threadIdx.x; n < N; n += blockDim.x) {
        int a;
        if (layout == 2)      a = (rf[n] != 0.0f);
        else if (layout == 1) a = (raw[n] != 0);
        else                  a = (ri[n] != 0);
        active[n] = a;
    }
    if (threadIdx.x == 0) meta[0] = layout;
}

// Decode enc + write out1/out2.
__global__ void outw_kernel(const unsigned long long* enc, const float* obs_r_ws,
                            float* out1, float* out2) {
    int t = blockIdx.x * 256 + threadIdx.x;
    if (t >= T) return;
    unsigned long long ev = enc[t];
    float best; int idx;
    if (ev == 0ULL) { best = -3.4e38f; idx = -1; }
    else {
        unsigned int e32 = (unsigned int)(ev >> 32);
        unsigned int bits = (e32 & 0x80000000u) ? (e32 & 0x7FFFFFFFu) : ~e32;
        best = __uint_as_float(bits);
        idx = (int)~((unsigned int)(ev & 0xFFFFFFFFu));
    }
    bool meaningful = obs_r_ws[t] > 0.05f;
    bool matched = meaningful && (best > 0.5f);
    out1[t] = matched ? best : 0.0f;
    out2[t] = matched ? (float)idx : -1.0f;
}

// ===========================================================================
// FAST PATH kernels
// ===========================================================================
__global__ void conv_hidden(const float* hidden, unsigned short* hb) {
    int e = blockIdx.x * 256 + threadIdx.x;     // [0, BT*256)
    int row = e >> 8, c8 = (e & 255) * 8;
    const float* src = hidden + (size_t)row * H + c8;
    float4 v0 = *(const float4*)src;
    float4 v1 = *(const float4*)(src + 4);
    uint4 o;
    o.x = f2bf(v0.x) | ((unsigned)f2bf(v0.y) << 16);
    o.y = f2bf(v0.z) | ((unsigned)f2bf(v0.w) << 16);
    o.z = f2bf(v1.x) | ((unsigned)f2bf(v1.y) << 16);
    o.w = f2bf(v1.z) | ((unsigned)f2bf(v1.w) << 16);
    *(uint4*)(hb + (size_t)row * H + c8) = o;
}

__global__ void conv_wb(const float* Wg1, const float* Wp1, const float* Wobs,
                        unsigned short* wb) {
    int e = blockIdx.x * 256 + threadIdx.x;     // [0, NALL*256)
    int row = e >> 8, c8 = (e & 255) * 8;
    const float* src = (row < 512) ? &Wg1[(size_t)row * H]
                     : (row < 1024) ? &Wp1[(size_t)(row - 512) * H]
                                    : &Wobs[(size_t)(row - 1024) * H];
    float4 v0 = *(const float4*)(src + c8);
    float4 v1 = *(const float4*)(src + c8 + 4);
    uint4 o;
    o.x = f2bf(v0.x) | ((unsigned)f2bf(v0.y) << 16);
    o.y = f2bf(v0.z) | ((unsigned)f2bf(v0.w) << 16);
    o.z = f2bf(v1.x) | ((unsigned)f2bf(v1.y) << 16);
    o.w = f2bf(v1.z) | ((unsigned)f2bf(v1.w) << 16);
    *(uint4*)(wb + (size_t)row * H + c8) = o;
}

__global__ void conv_vec(const float* b_g1, const float* b_p1, const float* W_g2,
                         const float* W_p2, float* b1c, float* w2c) {
    int c = threadIdx.x;
    if (c < 512) { b1c[c] = b_g1[c];       w2c[c] = W_g2[c]; }
    else         { b1c[c] = b_p1[c - 512]; w2c[c] = W_p2[c - 512]; }
}

__global__ void belprep_bf(const float* beliefs, unsigned short* belb) {
    int wave = (blockIdx.x * blockDim.x + threadIdx.x) >> 6;
    int lane = threadIdx.x & 63;
    if (wave >= N) return;
    float4 v = ((const float4*)(beliefs + (size_t)wave * D))[lane];
    float ss = v.x * v.x + v.y * v.y + v.z * v.z + v.w * v.w;
    for (int m = 1; m < 64; m <<= 1) ss += __shfl_xor(ss, m, 64);
    float inv = 1.0f / fmaxf(sqrtf(ss), 1e-8f);
    uint2 o;
    o.x = f2bf(v.x * inv) | ((unsigned)f2bf(v.y * inv) << 16);
    o.y = f2bf(v.z * inv) | ((unsigned)f2bf(v.w * inv) << 16);
    *(uint2*)(belb + (size_t)wave * D + lane * 4) = o;
}

// One MFMA GEMM for all projections: A = h_bf16 [16384][2048], B = wb [1280][2048].
// 128x128 tiles, BK=32, global_load_lds staging. Epilogue: MLP (relu+w2 dot ->
// atomicAdd y) or obs (atomicAdd obs_buf with B-mean fold).
__global__ __launch_bounds__(256) void big_gemm(const unsigned short* Ab, const unsigned short* Bb,
                                                const float* b1c, const float* w2c,
                                                float* yg, float* yp, float* obs_buf) {
    __shared__ unsigned short As[128 * 32];
    __shared__ unsigned short Bs[128 * 32];
    __shared__ float b1s[128], w2s[128];
    int tid = threadIdx.x;
    int mb = blockIdx.x, nb = blockIdx.y;
    int m0 = mb * 128, n0 = nb * 128;
    bool is_mlp = (nb < 8);
    if (is_mlp && tid < 128) { b1s[tid] = b1c[n0 + tid]; w2s[tid] = w2c[n0 + tid]; }
    int wave = tid >> 6, lane = tid & 63;
    int wr = wave >> 1, wc = wave & 1;
    int quad = lane >> 4, mrow = lane & 15;
    f32x4 acc[4][4] = {};
    const unsigned short* gA = Ab + (size_t)(m0 + (tid >> 2)) * H + (tid & 3) * 8;
    const unsigned short* gB = Bb + (size_t)(n0 + (tid >> 2)) * H + (tid & 3) * 8;
    char* lA = (char*)As + wave * 1024;
    char* lB = (char*)Bs + wave * 1024;
    for (int k0 = 0; k0 < H; k0 += 32) {
        async16(gA + k0, lA);
        async16(gA + (size_t)64 * H + k0, lA + 4096);
        async16(gB + k0, lB);
        async16(gB + (size_t)64 * H + k0, lB + 4096);
        __syncthreads();
        bf16x8 a[4], b[4];
        for (int i = 0; i < 4; i++) a[i] = *(const bf16x8*)&As[(wr * 64 + i * 16 + mrow) * 32 + quad * 8];
        for (int j = 0; j < 4; j++) b[j] = *(const bf16x8*)&Bs[(wc * 64 + j * 16 + mrow) * 32 + quad * 8];
        for (int i = 0; i < 4; i++)
            for (int j = 0; j < 4; j++)
                acc[i][j] = __builtin_amdgcn_mfma_f32_16x16x32_bf16(a[i], b[j], acc[i][j], 0, 0, 0);
        __syncthreads();
    }
    if (is_mlp) {
        float* y = (nb < 4) ? yg : yp;
        for (int i = 0; i < 4; i++) {
            int row_g = m0 + wr * 64 + i * 16 + quad * 4;
            for (int r = 0; r < 4; r++) {
                float s = 0.0f;
                for (int j = 0; j < 4; j++) {
                    int cl = wc * 64 + j * 16 + mrow;
                    float z = acc[i][j][r] + b1s[cl];
                    z = fmaxf(z, 0.0f);
                    s += z * w2s[cl];
                }
                s += __shfl_xor(s, 1); s += __shfl_xor(s, 2);
                s += __shfl_xor(s, 4); s += __shfl_xor(s, 8);
                if (mrow == 0) atomicAdd(&y[row_g + r], s);
            }
        }
    } else {
        for (int i = 0; i < 4; i++)
            for (int r = 0; r < 4; r++) {
                int row_g = m0 + wr * 64 + i * 16 + quad * 4 + r;
                int t = row_g & (T - 1);
                for (int j = 0; j < 4; j++) {
                    int d = n0 - 1024 + wc * 64 + j * 16 + mrow;
                    atomicAdd(&obs_buf[(size_t)t * D + d], acc[i][j][r] * 0.25f);
                }
            }
    }
}

// Per-token epilogue: approx pm, norms, out0, obs_ang bf16, flags + y-row zeroing.
__global__ void finalize_fast(const float* yg, const float* yp, const float* obs_buf,
                              const float* b_g2, const float* b_p2,
                              float* out0, float* out3, float* obs_r_ws, float* fac,
                              unsigned short* oab, int* flaglist, int* flagcnt,
                              float* yg_mut, float* yp_mut) {
    int t = blockIdx.x * 4 + (threadIdx.x >> 6);
    int lane = threadIdx.x & 63;
    if (t >= T) return;
    float bg2 = b_g2[0], bp2 = b_p2[0];
    float pm = 0.0f;
    for (int b = 0; b < B; ++b) {
        float g = yg[b * T + t] + bg2;
        float p = yp[b * T + t] + bp2;
        float gate = 1.0f / (1.0f + expf(-g));
        float prec = (p > 20.0f) ? p : log1pf(expf(p));
        pm += gate * prec;
    }
    pm *= 0.25f;
    float4 v = ((const float4*)(obs_buf + (size_t)t * D))[lane];
    float ss = v.x * v.x + v.y * v.y + v.z * v.z + v.w * v.w;
    for (int m = 1; m < 64; m <<= 1) ss += __shfl_xor(ss, m, 64);
    float norm = sqrtf(ss);
    float na = fmaxf(norm, 1e-8f);
    float f = norm / na;
    float inv = 1.0f / na;
    float ax = v.x * inv, ay = v.y * inv, az = v.z * inv, aw = v.w * inv;
    float4 ob; ob.x = ax * pm; ob.y = ay * pm; ob.z = az * pm; ob.w = aw * pm;
    ((float4*)(out0 + (size_t)t * D))[lane] = ob;
    uint2 oa;
    oa.x = f2bf(ax) | ((unsigned)f2bf(ay) << 16);
    oa.y = f2bf(az) | ((unsigned)f2bf(aw) << 16);
    *(uint2*)(oab + (size_t)t * D + lane * 4) = oa;
    if (lane == 0) {
        float obs_r = pm * f;
        obs_r_ws[t] = obs_r;
        fac[t] = f;
        out3[t] = (obs_r > 0.05f) ? 1.0f : 0.0f;
        // band = 8 sigma of the bf16-GEMM pm error (sigma ~ 1.4e-4)
        if (fabsf(obs_r - 0.05f) < 1.2e-3f) {
            int idx = atomicAdd(flagcnt, 1);
            if (idx < CAP) {
                flaglist[idx] = t;
                for (int b = 0; b < B; ++b) { yg_mut[b * T + t] = 0.0f; yp_mut[b * T + t] = 0.0f; }
            }
        }
    }
}

// Near-exact MLP recompute for flagged rows via compensated bf16 MFMA (bf16x3):
// x = hi + lo, acc = lo*whi + hi*wlo + hi*whi (fp32 accum) -> per-product residual
// ~(2^-9)^2, pm error ~1e-6. Tile M=64 x N=128, BK=32, 256 threads / 4 waves,
// hi/lo split done in-kernel from fp32 sources (no extra workspace).
__global__ __launch_bounds__(256) void refine_mfma(const float* hidden,
        const float* W_g1, const float* W_p1, const float* b1c, const float* w2c,
        const int* flaglist, const int* flagcnt, float* yg, float* yp) {
    int nrows = min(*flagcnt, CAP) * 4;
    int m0 = blockIdx.x * 64;
    if (m0 >= nrows) return;
    int nb = blockIdx.y;
    int n0 = nb * 128;
    __shared__ unsigned short Ahi[64 * 32], Alo[64 * 32];
    __shared__ unsigned short Bhi[128 * 32], Blo[128 * 32];
    __shared__ int rowg_s[64];
    __shared__ float b1s[128], w2s[128];
    int tid = threadIdx.x;
    if (tid < 64) {
        int fr = m0 + tid;
        int rg = -1;
        if (fr < nrows) { int tok = flaglist[fr >> 2]; rg = (fr & 3) * T + tok; }
        rowg_s[tid] = rg;
    } else if (tid >= 128) {
        int c = tid - 128;
        b1s[c] = b1c[n0 + c]; w2s[c] = w2c[n0 + c];
    }
    __syncthreads();
    const float* Wbase = (n0 < 512) ? W_g1 : W_p1;
    int wofs = n0 & 511;
    int arow = tid >> 2, kseg = (tid & 3) * 8;   // lane-contiguous 16B LDS chunks
    int argr = rowg_s[arow]; if (argr < 0) argr = 0;
    const float* aptr = hidden + (size_t)argr * H + kseg;
    const float* bptr0 = Wbase + (size_t)(wofs + arow) * H + kseg;        // rows 0-63
    const float* bptr1 = Wbase + (size_t)(wofs + arow + 64) * H + kseg;   // rows 64-127
    int wave = tid >> 6, lane = tid & 63;
    int quad = lane >> 4, mrow = lane & 15;
    f32x4 acc[4][2] = {};
    for (int k0 = 0; k0 < H; k0 += 32) {
        float xs[8];
        {   // A tile: 64 rows x 32 k
            float4 v0 = *(const float4*)(aptr + k0);
            float4 v1 = *(const float4*)(aptr + k0 + 4);
            xs[0]=v0.x; xs[1]=v0.y; xs[2]=v0.z; xs[3]=v0.w;
            xs[4]=v1.x; xs[5]=v1.y; xs[6]=v1.z; xs[7]=v1.w;
            unsigned short hi[8], lo[8];
            for (int q = 0; q < 8; q++) {
                hi[q] = f2bf(xs[q]);
                lo[q] = f2bf(xs[q] - bf2f(hi[q]));
            }
            uint4 ph, pl;
            ph.x = hi[0]|((unsigned)hi[1]<<16); ph.y = hi[2]|((unsigned)hi[3]<<16);
            ph.z = hi[4]|((unsigned)hi[5]<<16); ph.w = hi[6]|((unsigned)hi[7]<<16);
            pl.x = lo[0]|((unsigned)lo[1]<<16); pl.y = lo[2]|((unsigned)lo[3]<<16);
            pl.z = lo[4]|((unsigned)lo[5]<<16); pl.w = lo[6]|((unsigned)lo[7]<<16);
            *(uint4*)&Ahi[arow * 32 + kseg] = ph;
            *(uint4*)&Alo[arow * 32 + kseg] = pl;
        }
        for (int half = 0; half < 2; half++) {  // B tile: 128 rows x 32 k
            const float* bp = half ? bptr1 : bptr0;
            float4 v0 = *(const float4*)(bp + k0);
            float4 v1 = *(const float4*)(bp + k0 + 4);
            xs[0]=v0.x; xs[1]=v0.y; xs[2]=v0.z; xs[3]=v0.w;
            xs[4]=v1.x; xs[5]=v1.y; xs[6]=v1.z; xs[7]=v1.w;
            unsigned short hi[8], lo[8];
            for (int q = 0; q < 8; q++) {
                hi[q] = f2bf(xs[q]);
                lo[q] = f2bf(xs[q] - bf2f(hi[q]));
            }
            uint4 ph, pl;
            ph.x = hi[0]|((unsigned)hi[1]<<16); ph.y = hi[2]|((unsigned)hi[3]<<16);
            ph.z = hi[4]|((unsigned)hi[5]<<16); ph.w = hi[6]|((unsigned)hi[7]<<16);
            pl.x = lo[0]|((unsigned)lo[1]<<16); pl.y = lo[2]|((unsigned)lo[3]<<16);
            pl.z = lo[4]|((unsigned)lo[5]<<16); pl.w = lo[6]|((unsigned)lo[7]<<16);
            *(uint4*)&Bhi[(arow + half * 64) * 32 + kseg] = ph;
            *(uint4*)&Blo[(arow + half * 64) * 32 + kseg] = pl;
        }
        __syncthreads();
        bf16x8 ah[4], al[4], bh[2], bl[2];
        for (int i = 0; i < 4; i++) {
            ah[i] = *(const bf16x8*)&Ahi[(i * 16 + mrow) * 32 + quad * 8];
            al[i] = *(const bf16x8*)&Alo[(i * 16 + mrow) * 32 + quad * 8];
        }
        for (int j = 0; j < 2; j++) {
            bh[j] = *(const bf16x8*)&Bhi[(wave * 32 + j * 16 + mrow) * 32 + quad * 8];
            bl[j] = *(const bf16x8*)&Blo[(wave * 32 + j * 16 + mrow) * 32 + quad * 8];
        }
        for (int i = 0; i < 4; i++)
            for (int j = 0; j < 2; j++) {
                acc[i][j] = __builtin_amdgcn_mfma_f32_16x16x32_bf16(al[i], bh[j], acc[i][j], 0, 0, 0);
                acc[i][j] = __builtin_amdgcn_mfma_f32_16x16x32_bf16(ah[i], bl[j], acc[i][j], 0, 0, 0);
                acc[i][j] = __builtin_amdgcn_mfma_f32_16x16x32_bf16(ah[i], bh[j], acc[i][j], 0, 0, 0);
            }
        __syncthreads();
    }
    float* y = (nb < 4) ? yg : yp;
    for (int i = 0; i < 4; i++)
        for (int r = 0; r < 4; r++) {
            int row_l = i * 16 + quad * 4 + r;
            float s = 0.0f;
            for (int j = 0; j < 2; j++) {
                int cl = wave * 32 + j * 16 + mrow;
                float z = fmaxf(acc[i][j][r] + b1s[cl], 0.0f);
                s += z * w2s[cl];
            }
            s += __shfl_xor(s, 1); s += __shfl_xor(s, 2);
            s += __shfl_xor(s, 4); s += __shfl_xor(s, 8);
            if (mrow == 0) {
                int rg = rowg_s[row_l];
                if (rg >= 0) atomicAdd(&y[rg], s);
            }
        }
}

__global__ void refine_pm(const float* yg, const float* yp, const float* b_g2, const float* b_p2,
                          const int* flagcnt, const int* flaglist, const float* fac,
                          float* obs_r_ws, float* out3) {
    int nflag = min(*flagcnt, CAP);
    int idx = blockIdx.x * 64 + threadIdx.x;
    if (idx >= nflag) return;
    int t = flaglist[idx];
    float bg2 = b_g2[0], bp2 = b_p2[0];
    float pm = 0.0f;
    for (int b = 0; b < B; ++b) {
        float g = yg[b * T + t] + bg2;
        float p = yp[b * T + t] + bp2;
        float gate = 1.0f / (1.0f + expf(-g));
        float prec = (p > 20.0f) ? p : log1pf(expf(p));
        pm += gate * prec;
    }
    pm *= 0.25f;
    float obs_r = pm * fac[t];
    obs_r_ws[t] = obs_r;
    out3[t] = (obs_r > 0.05f) ? 1.0f : 0.0f;
}

// sims = obs_ang @ bel_ang^T (bf16 MFMA) with fused masked max/argmax epilogue.
__global__ __launch_bounds__(256) void sims_mfma(const unsigned short* oab, const unsigned short* belb,
                                                 const int* active, unsigned long long* enc) {
    __shared__ unsigned short As[128 * 32];
    __shared__ unsigned short Bs[128 * 32];
    __shared__ int acts[128];
    int tid = threadIdx.x;
    int mb = blockIdx.x, nb = blockIdx.y;
    int m0 = mb * 128, n0 = nb * 128;
    if (tid < 128) acts[tid] = active[n0 + tid];
    int wave = tid >> 6, lane = tid & 63;
    int wr = wave >> 1, wc = wave & 1;
    int quad = lane >> 4, mrow = lane & 15;
    f32x4 acc[4][4] = {};
    const unsigned short* gA = oab + (size_t)(m0 + (tid >> 2)) * D + (tid & 3) * 8;
    const unsigned short* gB = belb + (size_t)(n0 + (tid >> 2)) * D + (tid & 3) * 8;
    char* lA = (char*)As + wave * 1024;
    char* lB = (char*)Bs + wave * 1024;
    for (int k0 = 0; k0 < D; k0 += 32) {
        async16(gA + k0, lA);
        async16(gA + (size_t)64 * D + k0, lA + 4096);
        async16(gB + k0, lB);
        async16(gB + (size_t)64 * D + k0, lB + 4096);
        __syncthreads();
        bf16x8 a[4], b[4];
        for (int i = 0; i < 4; i++) a[i] = *(const bf16x8*)&As[(wr * 64 + i * 16 + mrow) * 32 + quad * 8];
        for (int j = 0; j < 4; j++) b[j] = *(const bf16x8*)&Bs[(wc * 64 + j * 16 + mrow) * 32 + quad * 8];
        for (int i = 0; i < 4; i++)
            for (int j = 0; j < 4; j++)
                acc[i][j] = __builtin_amdgcn_mfma_f32_16x16x32_bf16(a[i], b[j], acc[i][j], 0, 0, 0);
        __syncthreads();
    }
    for (int i = 0; i < 4; i++)
        for (int r = 0; r < 4; r++) {
            int row_g = m0 + wr * 64 + i * 16 + quad * 4 + r;
            unsigned long long best = 0ULL;
            for (int j = 0; j < 4; j++) {
                int cl = wc * 64 + j * 16 + mrow;
                if (acts[cl]) {
                    unsigned long long ev = enc_sim(acc[i][j][r], n0 + cl);
                    if (ev > best) best = ev;
                }
            }
            best = max(best, __shfl_xor(best, 1));
            best = max(best, __shfl_xor(best, 2));
            best = max(best, __shfl_xor(best, 4));
            best = max(best, __shfl_xor(best, 8));
            if (mrow == 0 && best) atomicMax(&enc[row_g], best);
        }
}

// ===========================================================================
// FALLBACK (round-1 fp32 pipeline, proven correct)
// ===========================================================================
__global__ void wt_kernel(const float* Wg1, const float* Wp1, const float* Wobs, float* WT) {
    __shared__ float tile[32][33];
    int hb = blockIdx.x * 32, cb = blockIdx.y * 32;
    int x = threadIdx.x & 31, y = threadIdx.x >> 5;
    for (int i = 0; i < 32; i += 8) {
        int c = cb + y + i;
        const float* src = (c < 512) ? &Wg1[(size_t)c * H]
                         : (c < 1024) ? &Wp1[(size_t)(c - 512) * H]
                                      : &Wobs[(size_t)(c - 1024) * H];
        tile[y + i][x] = src[hb + x];
    }
    __syncthreads();
    for (int i = 0; i < 32; i += 8)
        WT[(size_t)(hb + y + i) * WTC + cb + x] = tile[x][y + i];
}

__global__ void belprep_kernel(const float* beliefs, float* bel_ang) {
    int wave = (blockIdx.x * blockDim.x + threadIdx.x) >> 6;
    int lane = threadIdx.x & 63;
    if (wave >= N) return;
    float4 v = ((const float4*)(beliefs + (size_t)wave * D))[lane];
    float ss = v.x * v.x + v.y * v.y + v.z * v.z + v.w * v.w;
    for (int m = 1; m < 64; m <<= 1) ss += __shfl_xor(ss, m, 64);
    float inv = 1.0f / fmaxf(sqrtf(ss), 1e-8f);
    float4 o; o.x = v.x * inv; o.y = v.y * inv; o.z = v.z * inv; o.w = v.w * inv;
    ((float4*)(bel_ang + (size_t)wave * D))[lane] = o;
}

__global__ __launch_bounds__(256) void gemm_obs_kernel(const float* hidden, const float* WT,
                                                       float* obs_mean) {
    __shared__ float As[32][33];
    __shared__ float Ws[32][260];
    int t0 = blockIdx.x * 32;
    int tx = threadIdx.x & 63, ty = threadIdx.x >> 6;
    float acc[8][4] = {};
    for (int h0 = 0; h0 < H; h0 += 32) {
        for (int q = 0; q < 4; ++q) {
            int e = threadIdx.x + q * 256;
            int r = e >> 5, kk = e & 31;
            float s = 0.0f;
            for (int b = 0; b < B; ++b) s += hidden[((size_t)b * T + t0 + r) * H + h0 + kk];
            As[kk][r] = s;
        }
        for (int q = 0; q < 8; ++q) {
            int e4 = threadIdx.x + q * 256;
            int kk = e4 >> 6, c4 = (e4 & 63) * 4;
            *(float4*)&Ws[kk][c4] = *(const float4*)&WT[(size_t)(h0 + kk) * WTC + 1024 + c4];
        }
        __syncthreads();
        for (int kk = 0; kk < 32; ++kk) {
            float a[8], w[4];
            for (int i = 0; i < 8; i++) a[i] = As[kk][ty * 8 + i];
            for (int j = 0; j < 4; j++) w[j] = Ws[kk][tx + 64 * j];
            for (int i = 0; i < 8; i++)
                for (int j = 0; j < 4; j++) acc[i][j] += a[i] * w[j];
        }
        __syncthreads();
    }
    for (int i = 0; i < 8; i++)
        for (int j = 0; j < 4; j++)
            obs_mean[(size_t)(t0 + ty * 8 + i) * D + tx + 64 * j] = acc[i][j] * 0.25f;
}

__global__ __launch_bounds__(512, 4) void gemm_mlp_kernel(
        const float* hidden, const float* WT,
        const float* b1g, const float* b1p, const float* w2g, const float* w2p,
        const float* b2g, const float* b2p, float* yg, float* yp) {
    __shared__ float As[16][65];
    __shared__ float Ws[16][516];
    int R = blockIdx.x * 64;
    int path = blockIdx.y;
    int cbase = path * 512;
    int tx = threadIdx.x & 63, ty = threadIdx.x >> 6;
    float acc[8][8] = {};
    for (int h0 = 0; h0 < H; h0 += 16) {
        {   int r = threadIdx.x >> 3, k2 = (threadIdx.x & 7) * 2;
            float2 v = *(const float2*)&hidden[(size_t)(R + r) * H + h0 + k2];
            As[k2][r] = v.x; As[k2 + 1][r] = v.y; }
        for (int q = 0; q < 4; ++q) {
            int e4 = threadIdx.x + q * 512;
            int kk = e4 >> 7, c4 = (e4 & 127) * 4;
            *(float4*)&Ws[kk][c4] = *(const float4*)&WT[(size_t)(h0 + kk) * WTC + cbase + c4];
        }
        __syncthreads();
        for (int kk = 0; kk < 16; ++kk) {
            float a[8], w[8];
            for (int i = 0; i < 8; i++) a[i] = As[kk][ty * 8 + i];
            for (int j = 0; j < 8; j++) w[j] = Ws[kk][tx + 64 * j];
            for (int i = 0; i < 8; i++)
                for (int j = 0; j < 8; j++) acc[i][j] += a[i] * w[j];
        }
        __syncthreads();
    }
    const float* b1 = path ? b1p : b1g;
    const float* w2 = path ? w2p : w2g;
    float b2 = path ? b2p[0] : b2g[0];
    float part[8];
    for (int i = 0; i < 8; i++) {
        float s = 0.0f;
        for (int j = 0; j < 8; j++) {
            int c = tx + 64 * j;
            float z = fmaxf(acc[i][j] + b1[c], 0.0f);
            s += z * w2[c];
        }
        part[i] = s;
    }
    for (int m = 1; m < 64; m <<= 1)
        for (int i = 0; i < 8; i++) part[i] += __shfl_xor(part[i], m, 64);
    if (tx == 0) {
        float* dst = path ? yp : yg;
        for (int i = 0; i < 8; i++) dst[R + ty * 8 + i] = part[i] + b2;
    }
}

__global__ void finalize_kernel(const float* yg, const float* yp, float* obs,
                                float* out0, float* out3, float* obs_r_ws,
                                unsigned long long* enc) {
    int t = blockIdx.x * 4 + (threadIdx.x >> 6);
    int lane = threadIdx.x & 63;
    if (t >= T) return;
    float pm = 0.0f;
    for (int b = 0; b < B; ++b) {
        float g = yg[b * T + t], p = yp[b * T + t];
        float gate = 1.0f / (1.0f + expf(-g));
        float prec = (p > 15.0f) ? p : log1pf(expf(p));
        pm += gate * prec;
    }
    pm *= (1.0f / B);
    float4 v = ((const float4*)(obs + (size_t)t * D))[lane];
    float ss = v.x * v.x + v.y * v.y + v.z * v.z + v.w * v.w;
    for (int m = 1; m < 64; m <<= 1) ss += __shfl_xor(ss, m, 64);
    float norm = sqrtf(ss);
    float na = fmaxf(norm, 1e-8f);
    float4 ob;
    ob.x = v.x / na * pm; ob.y = v.y / na * pm;
    ob.z = v.z / na * pm; ob.w = v.w / na * pm;
    float obs_r = pm * (norm / na);
    ((float4*)(out0 + (size_t)t * D))[lane] = ob;
    float ra = fmaxf(obs_r, 1e-8f);
    float4 oa;
    oa.x = ob.x / ra; oa.y = ob.y / ra; oa.z = ob.z / ra; oa.w = ob.w / ra;
    ((float4*)(obs + (size_t)t * D))[lane] = oa;
    if (lane == 0) {
        out3[t] = (obs_r > 0.05f) ? 1.0f : 0.0f;
        obs_r_ws[t] = obs_r;
        enc[t] = 0ULL;
    }
}

__global__ __launch_bounds__(256) void sims_kernel(const float* obs_ang, const float* bel_ang,
                                                   const int* active, unsigned long long* enc) {
    __shared__ float Aos[64][68];
    __shared__ float Bbs[64][68];
    __shared__ unsigned long long lmax[64];
    __shared__ int act[64];
    int tb = blockIdx.x * 64, nb = blockIdx.y * 64;
    int tx = threadIdx.x & 15, ty = threadIdx.x >> 4;
    if (threadIdx.x < 64) { lmax[threadIdx.x] = 0ULL; act[threadIdx.x] = active[nb + threadIdx.x]; }
    float acc[4][4] = {};
    for (int d0 = 0; d0 < D; d0 += 64) {
        for (int q = 0; q < 4; ++q) {
            int e4 = threadIdx.x + q * 256;
            int r = e4 >> 4, c4 = (e4 & 15) * 4;
            *(float4*)&Aos[r][c4] = *(const float4*)&obs_ang[(size_t)(tb + r) * D + d0 + c4];
            *(float4*)&Bbs[r][c4] = *(const float4*)&bel_ang[(size_t)(nb + r) * D + d0 + c4];
        }
        __syncthreads();
        for (int dd = 0; dd < 64; ++dd) {
            float a[4], w[4];
            for (int i = 0; i < 4; i++) a[i] = Aos[ty + 16 * i][dd];
            for (int j = 0; j < 4; j++) w[j] = Bbs[tx + 16 * j][dd];
            for (int i = 0; i < 4; i++)
                for (int j = 0; j < 4; j++) acc[i][j] += a[i] * w[j];
        }
        __syncthreads();
    }
    for (int i = 0; i < 4; i++) {
        unsigned long long best = 0ULL;
        for (int j = 0; j < 4; j++) {
            int c = tx + 16 * j;
            if (act[c]) {
                unsigned long long ev = enc_sim(acc[i][j], nb + c);
                if (ev > best) best = ev;
            }
        }
        atomicMax(&lmax[ty + 16 * i], best);
    }
    __syncthreads();
    if (threadIdx.x < 64 && lmax[threadIdx.x])
        atomicMax(&enc[tb + threadIdx.x], lmax[threadIdx.x]);
}

// ===========================================================================
extern "C" void kernel_launch(void* const* d_in, const int* in_sizes, int n_in,
                              void* d_out, int out_size, void* d_ws, size_t ws_size,
                              hipStream_t stream) {
    const float* hidden  = (const float*)d_in[0];
    const float* beliefs = (const float*)d_in[1];
    const unsigned char* mask_raw = (const unsigned char*)d_in[2];
    const float* W_obs = (const float*)d_in[3];
    const float* W_g1  = (const float*)d_in[4];
    const float* b_g1  = (const float*)d_in[5];
    const float* W_g2  = (const float*)d_in[6];
    const float* b_g2  = (const float*)d_in[7];
    const float* W_p1  = (const float*)d_in[8];
    const float* b_p1  = (const float*)d_in[9];
    const float* W_p2  = (const float*)d_in[10];
    const float* b_p2  = (const float*)d_in[11];

    float* out0 = (float*)d_out;
    float* out1 = out0 + (size_t)T * D;
    float* out2 = out1 + T;
    float* out3 = out2 + T;
    char* ws = (char*)d_ws;

    if (ws_size >= WS_NEEDF) {
        // ---------------- fast path (bf16 MFMA + compensated refine) ----------------
        unsigned short* hb   = (unsigned short*)(ws + WS_HB);
        unsigned short* wb   = (unsigned short*)(ws + WS_WB);
        unsigned short* belb = (unsigned short*)(ws + WS_BELB);
        unsigned short* oab  = (unsigned short*)(ws + WS_OAB);
        float* b1c     = (float*)(ws + WS_B1C);
        float* w2c     = (float*)(ws + WS_W2C);
        float* fac     = (float*)(ws + WS_FAC);
        float* obs_r   = (float*)(ws + WS_OBSR);
        int*   flaglist= (int*)(ws + WS_FLAG);
        float* obs_buf = (float*)(ws + WS_OBS);
        float* yg      = (float*)(ws + WS_YG);
        float* yp      = (float*)(ws + WS_YP);
        unsigned long long* enc = (unsigned long long*)(ws + WS_ENC);
        int*   flagcnt = (int*)(ws + WS_CNT);
        int*   active  = (int*)(ws + WS_ACTV);
        int*   meta    = (int*)(ws + WS_META);

        hipMemsetAsync(ws + WS_OBS, 0, WS_ZEROSZ, stream);
        mask_kernel<<<1, 1024, 0, stream>>>(mask_raw, active, meta);
        conv_vec<<<1, 1024, 0, stream>>>(b_g1, b_p1, W_g2, W_p2, b1c, w2c);
        conv_wb<<<NALL, 256, 0, stream>>>(W_g1, W_p1, W_obs, wb);
        conv_hidden<<<BT, 256, 0, stream>>>(hidden, hb);
        belprep_bf<<<N / 4, 256, 0, stream>>>(beliefs, belb);
        big_gemm<<<dim3(BT / 128, NALL / 128), 256, 0, stream>>>(hb, wb, b1c, w2c, yg, yp, obs_buf);
        finalize_fast<<<T / 4, 256, 0, stream>>>(yg, yp, obs_buf, b_g2, b_p2,
                                                 out0, out3, obs_r, fac, oab,
                                                 flaglist, flagcnt, yg, yp);
        refine_mfma<<<dim3(CAP * 4 / 64, 8), 256, 0, stream>>>(hidden, W_g1, W_p1, b1c, w2c,
                                                               flaglist, flagcnt, yg, yp);
        refine_pm<<<CAP / 64, 64, 0, stream>>>(yg, yp, b_g2, b_p2, flagcnt, flaglist,
                                               fac, obs_r, out3);
        sims_mfma<<<dim3(T / 128, N / 128), 256, 0, stream>>>(oab, belb, active, enc);
        outw_kernel<<<(T + 255) / 256, 256, 0, stream>>>(enc, obs_r, out1, out2);
        return;
    }

    if (ws_size < F_NEED) return;
    // ---------------- fallback (round-1 fp32, proven) ----------------
    float* WT       = (float*)(ws + F_WT);
    float* bel_ang  = (float*)(ws + F_BEL);
    float* obs_buf  = (float*)(ws + F_OBS);
    float* yg       = (float*)(ws + F_YG);
    float* yp       = (float*)(ws + F_YP);
    float* obs_r_ws = (float*)(ws + F_OBSR);
    unsigned long long* enc = (unsigned long long*)(ws + F_ENC);
    int* active     = (int*)(ws + F_ACT);
    int* meta       = (int*)(ws + F_META);

    mask_kernel<<<1, 1024, 0, stream>>>(mask_raw, active, meta);
    wt_kernel<<<dim3(H / 32, WTC / 32), 256, 0, stream>>>(W_g1, W_p1, W_obs, WT);
    belprep_kernel<<<N / 4, 256, 0, stream>>>(beliefs, bel_ang);
    gemm_obs_kernel<<<T / 32, 256, 0, stream>>>(hidden, WT, obs_buf);
    gemm_mlp_kernel<<<dim3(BT / 64, 2), 512, 0, stream>>>(
        hidden, WT, b_g1, b_p1, W_g2, W_p2, b_g2, b_p2, yg, yp);
    finalize_kernel<<<T / 4, 256, 0, stream>>>(yg, yp, obs_buf, out0, out3, obs_r_ws, enc);
    sims_kernel<<<dim3(T / 64, N / 64), 256, 0, stream>>>(obs_buf, bel_ang, active, enc);
    outw_kernel<<<(T + 255) / 256, 256, 0, stream>>>(enc, obs_r_ws, out1, out2);
}